// Round 5
// baseline (474.810 us; speedup 1.0000x reference)
//
#include <hip/hip_runtime.h>
#include <hip/hip_bf16.h>

typedef float f32x4 __attribute__((ext_vector_type(4)));
typedef short bf16x8 __attribute__((ext_vector_type(8)));

#define BATCH 131072
#define SEQT  20

// ---------- fast activations ----------
__device__ __forceinline__ float fexp2(float x){ return __builtin_amdgcn_exp2f(x); }
__device__ __forceinline__ float frcp (float x){ return __builtin_amdgcn_rcpf(x); }

// ---------- bf16 helpers ----------
__device__ __forceinline__ unsigned short f2bf(float f){   // manual RNE (prologue-only paths)
  unsigned u = __float_as_uint(f);
  return (unsigned short)((u + 0x7fffu + ((u>>16)&1u)) >> 16);
}
// packed pair via HW cvt (compiler emits v_cvt_pk_bf16_f32)
__device__ __forceinline__ unsigned pk2c(float a, float b){
  union { __hip_bfloat162 h; unsigned u; } c;
  c.h = __float22bfloat162_rn(make_float2(a, b));
  return c.u;
}

__device__ __forceinline__ f32x4 MFMA(bf16x8 a, bf16x8 b, f32x4 c){
  return __builtin_amdgcn_mfma_f32_16x16x32_bf16(a, b, c, 0, 0, 0);
}
__device__ __forceinline__ bf16x8 zero8(){
  bf16x8 z;
#pragma unroll
  for (int e=0;e<8;++e) z[e]=0;
  return z;
}

// sigma column permutation: B-frag element e at lane-group kg holds hidden j = (e>>2)*16 + 4*kg + (e&3)
__device__ __forceinline__ int sigcol(int kg, int e){ return (e<4) ? (4*kg+e) : (16+4*kg+(e-4)); }

// A-frag builders from global f32 weights (staging + bottleneck)
__device__ __forceinline__ bf16x8 ldfragS(const float* __restrict__ W, int row, int kg){ // K=32, sigma cols
  bf16x8 f;
#pragma unroll
  for (int e=0;e<8;++e) f[e] = (short)f2bf(W[row*32 + sigcol(kg,e)]);
  return f;
}
__device__ __forceinline__ bf16x8 ldfragE(const float* __restrict__ W, int row, int kg){ // K=16 (latent)
  bf16x8 f;
#pragma unroll
  for (int e=0;e<8;++e) f[e] = (short)((e<4) ? f2bf(W[row*16 + 4*kg + e]) : (short)0);
  return f;
}

// ---------- gate nonlinearity + state update + sigma-pack ----------
// 7 trans/elem: 5 exp2 + 2 rcp (ig/fg share one rcp). cvt_pk packing.
__device__ __forceinline__ void activate(const f32x4* acc, float* cs, bf16x8& ph, bf16x8& phr){
  const float L1 = 1.4426950408889634f;
  float hv[8];
#pragma unroll
  for (int mm=0; mm<2; ++mm)
#pragma unroll
  for (int r=0; r<4; ++r){
    const int e = mm*4 + r;
    float zi = acc[0+mm][r];
    float zf = acc[2+mm][r];
    float zg = acc[4+mm][r];
    float zo = acc[6+mm][r];
    float A  = fexp2(-L1*zi);
    float F  = fexp2(-L1*zf);
    float B  = fexp2(2.0f*L1*zg);
    float ab = (1.0f+A)*(B+1.0f);
    float fp = 1.0f+F;
    float r1 = frcp(ab*fp);
    float ig = (B-1.0f)*fp*r1;     // sigm(zi)*tanh(zg)
    float fg = ab*r1;              // sigm(zf)... wait: fg = 1/(1+F) = ab*r1  ✓
    float cn = fmaf(fg, cs[e], ig);
    cs[e] = cn;
    float E  = fexp2(-L1*zo);
    float D  = fexp2(2.0f*L1*cn);
    hv[e] = (D-1.0f)*frcp((1.0f+E)*(D+1.0f));   // sigm(zo)*tanh(cn)
  }
  union U8 { unsigned u[4]; bf16x8 v; };
  U8 P, R;
  P.u[0] = pk2c(hv[0], hv[1]);
  P.u[1] = pk2c(hv[2], hv[3]);
  P.u[2] = pk2c(hv[4], hv[5]);
  P.u[3] = pk2c(hv[6], hv[7]);
#pragma unroll
  for (int p=0; p<4; ++p){
    float q0 = __uint_as_float(P.u[p] << 16);
    float q1 = __uint_as_float(P.u[p] & 0xffff0000u);
    R.u[p] = pk2c(hv[2*p] - q0, hv[2*p+1] - q1);
  }
  ph  = P.v;
  phr = R.v;
}

__global__ __launch_bounds__(256, 5) void lstm_ae_mfma(
    const float* __restrict__ x,
    const float* __restrict__ eWih0, const float* __restrict__ eWhh0,
    const float* __restrict__ ebih0, const float* __restrict__ ebhh0,
    const float* __restrict__ eWih1, const float* __restrict__ eWhh1,
    const float* __restrict__ ebih1, const float* __restrict__ ebhh1,
    const float* __restrict__ bnW,   const float* __restrict__ bnB,
    const float* __restrict__ exW,   const float* __restrict__ exB,
    const float* __restrict__ dWih0, const float* __restrict__ dWhh0,
    const float* __restrict__ dbih0, const float* __restrict__ dbhh0,
    const float* __restrict__ dWih1, const float* __restrict__ dWhh1,
    const float* __restrict__ dbih1, const float* __restrict__ dbhh1,
    const float* __restrict__ outW,  const float* __restrict__ outB,
    float* __restrict__ out)
{
  const int tid  = threadIdx.x;
  const int lane = tid & 63;
  const int w    = tid >> 6;      // wave id (0..3)
  const int cl   = lane & 15;     // batch col within wave / A-frag row
  const int kg   = lane >> 4;     // k-group (0..3)

  // LDS: biases (+16B zero slot) + weight-fragment region (enc/dec shared) ≈ 29 KB
  __shared__ __align__(16) float          sb[592];
  __shared__ __align__(16) unsigned short sfrag[13312];   // 1664 frags x 16B

  // ---- bias prep (bih+bhh summed) ----
  if (tid < 128){
    sb[      tid] = ebih0[tid] + ebhh0[tid];
    sb[128 + tid] = ebih1[tid] + ebhh1[tid];
    sb[256 + tid] = dbih0[tid] + dbhh0[tid];
    sb[384 + tid] = dbih1[tid] + dbhh1[tid];
  }
  if (tid < 16){
    sb[512 + tid] = (tid < 5) ? outB[tid] : 0.0f;
    sb[528 + tid] = bnB[tid];
  }
  if (tid < 32) sb[544 + tid] = exB[tid];
  if (tid < 16) sb[576 + tid] = 0.0f;          // 16B+ zero slot

  // ---- stage ENCODER weight frags into LDS ----
  // layout (16B frag units): [0]=Whh0 (8m x 64lane), [512]=Wih1, [1024]=Whh1, [1536]=Wih0 (8m x 16cl)
#pragma unroll
  for (int q=0; q<6; ++q){
    int tile = w + 4*q;                 // 0..23
    int mat  = tile >> 3, m = tile & 7;
    const float* Wm = (mat==0) ? eWhh0 : (mat==1) ? eWih1 : eWhh1;
    bf16x8 f = ldfragS(Wm, m*16+cl, kg);
    *(bf16x8*)&sfrag[(mat*512 + m*64 + lane)*8] = f;
  }
  if (tid < 128){
    int m = tid >> 4, r = tid & 15;
    bf16x8 f;
#pragma unroll
    for (int e=0;e<8;++e) f[e] = (short)((e<5) ? f2bf(eWih0[(m*16+r)*5+e]) : (short)0);
    *(bf16x8*)&sfrag[(1536 + m*16 + r)*8] = f;
  }
  __syncthreads();

  f32x4 acc[8];
  float cs0[8], cs1[8];
#pragma unroll
  for (int e=0;e<8;++e){ cs0[e]=0.f; cs1[e]=0.f; }
  bf16x8 ph0 = zero8(), ph0r = zero8(), ph1 = zero8(), ph1r = zero8();

  // Wih0 frag address: kg==0 lanes real, others the 16B zero slot (stride 0)
  const unsigned short* wih0p = (kg==0) ? &sfrag[(1536 + cl)*8] : (const unsigned short*)&sb[576];
  const unsigned wih0s = (kg==0) ? 128u : 0u;   // per-m stride in shorts

  // ---- x direct-from-global with 1-iteration software prefetch (kg==0 lanes only) ----
  const long blockb = (long)blockIdx.x * 64;
  const float* __restrict__ xcol = x + (blockb + w*16 + cl)*100;
  float xv0=0.f,xv1=0.f,xv2=0.f,xv3=0.f,xv4=0.f;
  if (kg==0){ xv0=xcol[0]; xv1=xcol[1]; xv2=xcol[2]; xv3=xcol[3]; xv4=xcol[4]; }

  // ================= encoder =================
  for (int t=0; t<SEQT; ++t){
    asm volatile("" ::: "memory");     // keep LDS reads in-loop; pins prefetch placement
    // prefetch x for t+1
    float xn0=0.f,xn1=0.f,xn2=0.f,xn3=0.f,xn4=0.f;
    if (kg==0 && t<SEQT-1){
      const float* xp = xcol + (t+1)*5;
      xn0=xp[0]; xn1=xp[1]; xn2=xp[2]; xn3=xp[3]; xn4=xp[4];
    }
    // build x frag for this step
    bf16x8 xf = zero8();
    if (kg==0){
      union { unsigned u[4]; bf16x8 v; } X;
      X.u[0] = pk2c(xv0,xv1);
      X.u[1] = pk2c(xv2,xv3);
      X.u[2] = pk2c(xv4,0.f);
      X.u[3] = 0u;
      xf = X.v;
    }

    // enc layer 0
#pragma unroll
    for (int m=0; m<8; ++m){
      bf16x8 fa = *(const bf16x8*)&sfrag[(m*64 + lane)*8];
      f32x4 b = *(const f32x4*)&sb[0 + m*16 + kg*4];
      b = MFMA(fa, ph0r, b);
      b = MFMA(fa, ph0 , b);
      acc[m] = b;
    }
#pragma unroll
    for (int m=0; m<8; ++m){
      bf16x8 fb = *(const bf16x8*)&wih0p[m*wih0s];
      acc[m] = MFMA(fb, xf, acc[m]);
    }
    activate(acc, cs0, ph0, ph0r);

    // enc layer 1
#pragma unroll
    for (int m=0; m<8; ++m){
      bf16x8 fd = *(const bf16x8*)&sfrag[(1024 + m*64 + lane)*8];
      bf16x8 fc = *(const bf16x8*)&sfrag[( 512 + m*64 + lane)*8];
      f32x4 b = *(const f32x4*)&sb[128 + m*16 + kg*4];
      b = MFMA(fd, ph1r, b);
      b = MFMA(fd, ph1 , b);
      b = MFMA(fc, ph0r, b);
      b = MFMA(fc, ph0 , b);
      acc[m] = b;
    }
    activate(acc, cs1, ph1, ph1r);

    xv0=xn0; xv1=xn1; xv2=xn2; xv3=xn3; xv4=xn4;
  }
  __syncthreads();   // all waves done with enc frags

  // ---- stage DECODER weight frags (overwrites enc region) ----
#pragma unroll
  for (int q=0; q<6; ++q){
    int tile = w + 4*q;
    int mat  = tile >> 3, m = tile & 7;
    const float* Wm = (mat==0) ? dWhh0 : (mat==1) ? dWih1 : dWhh1;
    bf16x8 f = ldfragS(Wm, m*16+cl, kg);
    *(bf16x8*)&sfrag[(mat*512 + m*64 + lane)*8] = f;
  }
  if (tid < 64){
    int r2 = tid & 15, k2 = tid >> 4;
    bf16x8 f = (r2 < 5) ? ldfragS(outW, r2, k2) : zero8();
    *(bf16x8*)&sfrag[(1536 + tid)*8] = f;
  }

  // ---- bottleneck (registers + global weight reads only) ----
  f32x4 dpre[8];
  {
    bf16x8 WBN = ldfragS(bnW, cl, kg);
    f32x4 aL = *(const f32x4*)&sb[528 + kg*4];
    aL = MFMA(WBN, ph1r, aL);
    aL = MFMA(WBN, ph1 , aL);
    bf16x8 ltf = zero8(), ltr = zero8();
#pragma unroll
    for (int r=0; r<4; ++r){
      float v = fmaxf(aL[r], 0.0f);
      unsigned short hb = f2bf(v);
      ltf[r] = (short)hb;
      ltr[r] = (short)f2bf(v - __uint_as_float(((unsigned)hb)<<16));
    }
    f32x4 aE[2];
#pragma unroll
    for (int m=0; m<2; ++m){
      bf16x8 WE = ldfragE(exW, m*16+cl, kg);
      f32x4 b = *(const f32x4*)&sb[544 + m*16 + kg*4];
      b = MFMA(WE, ltr, b);
      b = MFMA(WE, ltf, b);
      aE[m] = b;
    }
    bf16x8 exf = zero8(), exr = zero8();
#pragma unroll
    for (int e=0; e<8; ++e){
      float v = fmaxf(aE[e>>2][e&3], 0.0f);
      unsigned short hb = f2bf(v);
      exf[e] = (short)hb;
      exr[e] = (short)f2bf(v - __uint_as_float(((unsigned)hb)<<16));
    }
#pragma unroll
    for (int m=0; m<8; ++m){
      bf16x8 wm = ldfragS(dWih0, m*16+cl, kg);
      f32x4 b = *(const f32x4*)&sb[256 + m*16 + kg*4];
      b = MFMA(wm, exr, b);
      b = MFMA(wm, exf, b);
      dpre[m] = b;
    }
  }

  // reset state
#pragma unroll
  for (int e=0;e<8;++e){ cs0[e]=0.f; cs1[e]=0.f; }
  ph0 = zero8(); ph0r = zero8(); ph1 = zero8(); ph1r = zero8();

  __syncthreads();   // dec frags staged

  const f32x4 obias = *(const f32x4*)&sb[512 + kg*4];
  float* __restrict__ obp = out + (blockb + w*16 + cl)*100;

  // ================= decoder =================
  for (int t=0; t<SEQT; ++t){
    asm volatile("" ::: "memory");
    // dec layer 0: acc = dpre + Whh0d@(h0+res)
#pragma unroll
    for (int m=0; m<8; ++m){
      bf16x8 fa = *(const bf16x8*)&sfrag[(m*64 + lane)*8];
      f32x4 b = dpre[m];
      b = MFMA(fa, ph0r, b);
      b = MFMA(fa, ph0 , b);
      acc[m] = b;
    }
    activate(acc, cs0, ph0, ph0r);

    // dec layer 1
#pragma unroll
    for (int m=0; m<8; ++m){
      bf16x8 fd = *(const bf16x8*)&sfrag[(1024 + m*64 + lane)*8];
      bf16x8 fc = *(const bf16x8*)&sfrag[( 512 + m*64 + lane)*8];
      f32x4 b = *(const f32x4*)&sb[384 + m*16 + kg*4];
      b = MFMA(fd, ph1r, b);
      b = MFMA(fd, ph1 , b);
      b = MFMA(fc, ph0r, b);
      b = MFMA(fc, ph0 , b);
      acc[m] = b;
    }
    activate(acc, cs1, ph1, ph1r);

    // output projection (one padded tile, rows 0..4 live)
    bf16x8 fo = *(const bf16x8*)&sfrag[(1536 + lane)*8];
    f32x4 o = obias;
    o = MFMA(fo, ph1r, o);
    o = MFMA(fo, ph1 , o);
    float* op = obp + t*5;
    if (kg == 0){
      op[0] = o[0]; op[1] = o[1]; op[2] = o[2]; op[3] = o[3];
    } else if (kg == 1){
      op[4] = o[0];
    }
  }
}

extern "C" void kernel_launch(void* const* d_in, const int* in_sizes, int n_in,
                              void* d_out, int out_size, void* d_ws, size_t ws_size,
                              hipStream_t stream)
{
  const float* x     = (const float*)d_in[0];
  const float* eWih0 = (const float*)d_in[1];
  const float* eWhh0 = (const float*)d_in[2];
  const float* ebih0 = (const float*)d_in[3];
  const float* ebhh0 = (const float*)d_in[4];
  const float* eWih1 = (const float*)d_in[5];
  const float* eWhh1 = (const float*)d_in[6];
  const float* ebih1 = (const float*)d_in[7];
  const float* ebhh1 = (const float*)d_in[8];
  const float* bnW   = (const float*)d_in[9];
  const float* bnB   = (const float*)d_in[10];
  const float* exW   = (const float*)d_in[11];
  const float* exB   = (const float*)d_in[12];
  const float* dWih0 = (const float*)d_in[13];
  const float* dWhh0 = (const float*)d_in[14];
  const float* dbih0 = (const float*)d_in[15];
  const float* dbhh0 = (const float*)d_in[16];
  const float* dWih1 = (const float*)d_in[17];
  const float* dWhh1 = (const float*)d_in[18];
  const float* dbih1 = (const float*)d_in[19];
  const float* dbhh1 = (const float*)d_in[20];
  const float* outW  = (const float*)d_in[21];
  const float* outB  = (const float*)d_in[22];

  dim3 grid(BATCH / 64), block(256);
  hipLaunchKernelGGL(lstm_ae_mfma, grid, block, 0, stream,
                     x,
                     eWih0, eWhh0, ebih0, ebhh0,
                     eWih1, eWhh1, ebih1, ebhh1,
                     bnW, bnB, exW, exB,
                     dWih0, dWhh0, dbih0, dbhh0,
                     dWih1, dWhh1, dbih1, dbhh1,
                     outW, outB,
                     (float*)d_out);
}

// Round 6
// 446.738 us; speedup vs baseline: 1.0628x; 1.0628x over previous
//
#include <hip/hip_runtime.h>
#include <hip/hip_bf16.h>

typedef float f32x4 __attribute__((ext_vector_type(4)));
typedef short bf16x8 __attribute__((ext_vector_type(8)));

#define BATCH 131072
#define SEQT  20
#define L1F  1.4426950408889634f   // log2(e)
#define L2F  2.8853900817779268f   // 2*log2(e)

// ---------- fast activations ----------
__device__ __forceinline__ float fexp2(float x){ return __builtin_amdgcn_exp2f(x); }
__device__ __forceinline__ float frcp (float x){ return __builtin_amdgcn_rcpf(x); }

// ---------- bf16 helpers ----------
__device__ __forceinline__ unsigned short f2bf(float f){   // manual RNE (staging paths)
  unsigned u = __float_as_uint(f);
  return (unsigned short)((u + 0x7fffu + ((u>>16)&1u)) >> 16);
}
__device__ __forceinline__ unsigned pk2c(float a, float b){ // v_cvt_pk_bf16_f32
  union { __hip_bfloat162 h; unsigned u; } c;
  c.h = __float22bfloat162_rn(make_float2(a, b));
  return c.u;
}

__device__ __forceinline__ f32x4 MFMA(bf16x8 a, bf16x8 b, f32x4 c){
  return __builtin_amdgcn_mfma_f32_16x16x32_bf16(a, b, c, 0, 0, 0);
}
__device__ __forceinline__ bf16x8 zero8(){
  bf16x8 z;
#pragma unroll
  for (int e=0;e<8;++e) z[e]=0;
  return z;
}

// sigma column permutation: B-frag element e at lane-group kg holds hidden j = (e>>2)*16 + 4*kg + (e&3)
__device__ __forceinline__ int sigcol(int kg, int e){ return (e<4) ? (4*kg+e) : (16+4*kg+(e-4)); }

// A-frag builders from global f32 weights (staging + bottleneck); sc = pre-scale
__device__ __forceinline__ bf16x8 ldfragS(const float* __restrict__ W, int row, int kg, float sc){
  bf16x8 f;
#pragma unroll
  for (int e=0;e<8;++e) f[e] = (short)f2bf(sc * W[row*32 + sigcol(kg,e)]);
  return f;
}
__device__ __forceinline__ bf16x8 ldfragE(const float* __restrict__ W, int row, int kg){ // K=16 (latent)
  bf16x8 f;
#pragma unroll
  for (int e=0;e<8;++e) f[e] = (short)((e<4) ? f2bf(W[row*16 + 4*kg + e]) : (short)0);
  return f;
}

// ---------- gate nonlinearity + state update + sigma-pack ----------
// Pre-scaled z (i,f,o by log2e; g by 2log2e): 5 exp2 + 2 rcp, no lead-in muls.
__device__ __forceinline__ void activate(const f32x4* acc, float* cs, bf16x8& ph, bf16x8& phr){
  float hv[8];
#pragma unroll
  for (int mm=0; mm<2; ++mm)
#pragma unroll
  for (int r=0; r<4; ++r){
    const int e = mm*4 + r;
    float zi = acc[0+mm][r];
    float zf = acc[2+mm][r];
    float zg = acc[4+mm][r];
    float zo = acc[6+mm][r];
    float A  = fexp2(-zi);            // e^-zi
    float F  = fexp2(-zf);            // e^-zf
    float B  = fexp2(zg);             // e^(2 zg)
    float ab = (1.0f+A)*(B+1.0f);
    float fp = 1.0f+F;
    float r1 = frcp(ab*fp);
    float cn = fmaf(ab*r1, cs[e], (B-1.0f)*fp*r1);  // fg*c + sigm(zi)*tanh(zg)
    cs[e] = cn;
    float E  = fexp2(-zo);            // e^-zo
    float D  = fexp2(L2F*cn);         // e^(2 cn)
    hv[e] = (D-1.0f)*frcp((1.0f+E)*(D+1.0f));       // sigm(zo)*tanh(cn)
  }
  union U8 { unsigned u[4]; bf16x8 v; };
  U8 P, R;
  P.u[0] = pk2c(hv[0], hv[1]);
  P.u[1] = pk2c(hv[2], hv[3]);
  P.u[2] = pk2c(hv[4], hv[5]);
  P.u[3] = pk2c(hv[6], hv[7]);
#pragma unroll
  for (int p=0; p<4; ++p){
    float q0 = __uint_as_float(P.u[p] << 16);
    float q1 = __uint_as_float(P.u[p] & 0xffff0000u);
    R.u[p] = pk2c(hv[2*p] - q0, hv[2*p+1] - q1);
  }
  ph  = P.v;
  phr = R.v;
}

__global__ __launch_bounds__(256, 3) void lstm_ae_mfma(
    const float* __restrict__ x,
    const float* __restrict__ eWih0, const float* __restrict__ eWhh0,
    const float* __restrict__ ebih0, const float* __restrict__ ebhh0,
    const float* __restrict__ eWih1, const float* __restrict__ eWhh1,
    const float* __restrict__ ebih1, const float* __restrict__ ebhh1,
    const float* __restrict__ bnW,   const float* __restrict__ bnB,
    const float* __restrict__ exW,   const float* __restrict__ exB,
    const float* __restrict__ dWih0, const float* __restrict__ dWhh0,
    const float* __restrict__ dbih0, const float* __restrict__ dbhh0,
    const float* __restrict__ dWih1, const float* __restrict__ dWhh1,
    const float* __restrict__ dbih1, const float* __restrict__ dbhh1,
    const float* __restrict__ outW,  const float* __restrict__ outB,
    float* __restrict__ out)
{
  const int tid  = threadIdx.x;
  const int lane = tid & 63;
  const int w    = tid >> 6;      // wave id (0..3)
  const int cl   = lane & 15;     // batch col within wave / A-frag row
  const int kg   = lane >> 4;     // k-group (0..3)

  // LDS: biases (+zero slot) + weight frags (enc/dec shared) + 10-step output staging
  __shared__ __align__(16) float          sb[592];
  __shared__ __align__(16) unsigned short sfrag[13312];   // 1664 frags x 16B = 26.6 KB
  __shared__ __align__(16) float          sout[3200];     // 64 bb x 10 t x 5 f = 12.8 KB

  // ---- bias prep (bih+bhh, pre-scaled: g rows x2log2e, others xlog2e) ----
  if (tid < 128){
    float sc = (tid >= 64 && tid < 96) ? L2F : L1F;
    sb[      tid] = sc*(ebih0[tid] + ebhh0[tid]);
    sb[128 + tid] = sc*(ebih1[tid] + ebhh1[tid]);
    sb[256 + tid] = sc*(dbih0[tid] + dbhh0[tid]);
    sb[384 + tid] = sc*(dbih1[tid] + dbhh1[tid]);
  }
  if (tid < 16){
    sb[512 + tid] = (tid < 5) ? outB[tid] : 0.0f;
    sb[528 + tid] = bnB[tid];
  }
  if (tid < 32) sb[544 + tid] = exB[tid];
  if (tid < 16) sb[576 + tid] = 0.0f;          // 16B zero slot

  // ---- stage ENCODER weight frags (pre-scaled) ----
  // [0]=Whh0 (8m x 64lane), [512]=Wih1, [1024]=Whh1, [1536]=Wih0 (8m x 16cl)
#pragma unroll
  for (int q=0; q<6; ++q){
    int tile = w + 4*q;                 // 0..23
    int mat  = tile >> 3, m = tile & 7;
    float sc = (m==4 || m==5) ? L2F : L1F;
    const float* Wm = (mat==0) ? eWhh0 : (mat==1) ? eWih1 : eWhh1;
    bf16x8 f = ldfragS(Wm, m*16+cl, kg, sc);
    *(bf16x8*)&sfrag[(mat*512 + m*64 + lane)*8] = f;
  }
  if (tid < 128){
    int m = tid >> 4, r = tid & 15;
    float sc = (m==4 || m==5) ? L2F : L1F;
    bf16x8 f;
#pragma unroll
    for (int e=0;e<8;++e) f[e] = (short)((e<5) ? f2bf(sc*eWih0[(m*16+r)*5+e]) : (short)0);
    *(bf16x8*)&sfrag[(1536 + m*16 + r)*8] = f;
  }
  __syncthreads();

  // ---- preload biases into registers (survive the per-iter clobber) ----
  f32x4 rb0[8], rb1[8];
#pragma unroll
  for (int m=0;m<8;++m){
    rb0[m] = *(const f32x4*)&sb[      m*16 + kg*4];
    rb1[m] = *(const f32x4*)&sb[128 + m*16 + kg*4];
  }

  f32x4 acc[8], accB[8];
  float cs0[8], cs1[8];
#pragma unroll
  for (int e=0;e<8;++e){ cs0[e]=0.f; cs1[e]=0.f; }
  bf16x8 ph0 = zero8(), ph0r = zero8(), ph1 = zero8(), ph1r = zero8();

  // Wih0 frag address: kg==0 lanes real, others the 16B zero slot (stride 0)
  const unsigned short* wih0p = (kg==0) ? &sfrag[(1536 + cl)*8] : (const unsigned short*)&sb[576];
  const unsigned wih0s = (kg==0) ? 128u : 0u;   // per-m stride in shorts

  const long blockb = (long)blockIdx.x * 64;
  const float* __restrict__ xcol = x + (blockb + w*16 + cl)*100;

  // ---- encoder prologue: t=0 layer0 (h0=0 -> z0 = bias + Wih0@x0) ----
  bf16x8 xf = zero8();
  if (kg==0){
    union { unsigned u[4]; bf16x8 v; } X;
    X.u[0] = pk2c(xcol[0], xcol[1]);
    X.u[1] = pk2c(xcol[2], xcol[3]);
    X.u[2] = pk2c(xcol[4], 0.f);
    X.u[3] = 0u;
    xf = X.v;
  }
#pragma unroll
  for (int m=0; m<8; ++m){
    bf16x8 fb = *(const bf16x8*)&wih0p[m*wih0s];
    acc[m] = MFMA(fb, xf, rb0[m]);
  }
  activate(acc, cs0, ph0, ph0r);
  float xv0=0.f,xv1=0.f,xv2=0.f,xv3=0.f,xv4=0.f;   // x(t+1)
  if (kg==0){ xv0=xcol[5]; xv1=xcol[6]; xv2=xcol[7]; xv3=xcol[8]; xv4=xcol[9]; }

  // ================= encoder main (t = 0..18) =================
#pragma unroll 1
  for (int t=0; t<SEQT-1; ++t){
    asm volatile("" ::: "memory");
    // prefetch x(t+2)
    float xn0=0.f,xn1=0.f,xn2=0.f,xn3=0.f,xn4=0.f;
    if (kg==0 && t < SEQT-2){
      const float* xp = xcol + (t+2)*5;
      xn0=xp[0]; xn1=xp[1]; xn2=xp[2]; xn3=xp[3]; xn4=xp[4];
    }
    // layer1 MFMAs for step t (uses ph1(t-1), ph0(t))
#pragma unroll
    for (int m=0; m<8; ++m){
      bf16x8 fd = *(const bf16x8*)&sfrag[(1024 + m*64 + lane)*8];
      bf16x8 fc = *(const bf16x8*)&sfrag[( 512 + m*64 + lane)*8];
      f32x4 b = rb1[m];
      b = MFMA(fd, ph1r, b);
      b = MFMA(fd, ph1 , b);
      b = MFMA(fc, ph0r, b);
      b = MFMA(fc, ph0 , b);
      accB[m] = b;
    }
    // layer0 MFMAs for step t+1 (uses ph0(t), x(t+1)) — overlaps activate1
    if (kg==0){
      union { unsigned u[4]; bf16x8 v; } X;
      X.u[0] = pk2c(xv0,xv1);
      X.u[1] = pk2c(xv2,xv3);
      X.u[2] = pk2c(xv4,0.f);
      X.u[3] = 0u;
      xf = X.v;
    }
#pragma unroll
    for (int m=0; m<8; ++m){
      bf16x8 fa = *(const bf16x8*)&sfrag[(m*64 + lane)*8];
      bf16x8 fb = *(const bf16x8*)&wih0p[m*wih0s];
      f32x4 b = rb0[m];
      b = MFMA(fa, ph0r, b);
      b = MFMA(fa, ph0 , b);
      b = MFMA(fb, xf  , b);
      acc[m] = b;
    }
    activate(accB, cs1, ph1, ph1r);
    activate(acc,  cs0, ph0, ph0r);
    xv0=xn0; xv1=xn1; xv2=xn2; xv3=xn3; xv4=xn4;
  }
  // encoder epilogue: t=19 layer1 only
  {
#pragma unroll
    for (int m=0; m<8; ++m){
      bf16x8 fd = *(const bf16x8*)&sfrag[(1024 + m*64 + lane)*8];
      bf16x8 fc = *(const bf16x8*)&sfrag[( 512 + m*64 + lane)*8];
      f32x4 b = rb1[m];
      b = MFMA(fd, ph1r, b);
      b = MFMA(fd, ph1 , b);
      b = MFMA(fc, ph0r, b);
      b = MFMA(fc, ph0 , b);
      accB[m] = b;
    }
    activate(accB, cs1, ph1, ph1r);
  }
  __syncthreads();   // all waves done with enc frags

  // ---- stage DECODER weight frags (overwrites enc region; pre-scaled) ----
#pragma unroll
  for (int q=0; q<6; ++q){
    int tile = w + 4*q;
    int mat  = tile >> 3, m = tile & 7;
    float sc = (m==4 || m==5) ? L2F : L1F;
    const float* Wm = (mat==0) ? dWhh0 : (mat==1) ? dWih1 : dWhh1;
    bf16x8 f = ldfragS(Wm, m*16+cl, kg, sc);
    *(bf16x8*)&sfrag[(mat*512 + m*64 + lane)*8] = f;
  }
  if (tid < 64){
    int r2 = tid & 15, k2 = tid >> 4;
    bf16x8 f = (r2 < 5) ? ldfragS(outW, r2, k2, 1.0f) : zero8();
    *(bf16x8*)&sfrag[(1536 + tid)*8] = f;
  }

  // ---- bottleneck (registers + global weight reads; unscaled weights) ----
  f32x4 dpre[8];
  {
    bf16x8 WBN = ldfragS(bnW, cl, kg, 1.0f);
    f32x4 aL = *(const f32x4*)&sb[528 + kg*4];
    aL = MFMA(WBN, ph1r, aL);
    aL = MFMA(WBN, ph1 , aL);
    bf16x8 ltf = zero8(), ltr = zero8();
#pragma unroll
    for (int r=0; r<4; ++r){
      float v = fmaxf(aL[r], 0.0f);
      unsigned short hb = f2bf(v);
      ltf[r] = (short)hb;
      ltr[r] = (short)f2bf(v - __uint_as_float(((unsigned)hb)<<16));
    }
    f32x4 aE[2];
#pragma unroll
    for (int m=0; m<2; ++m){
      bf16x8 WE = ldfragE(exW, m*16+cl, kg);
      f32x4 b = *(const f32x4*)&sb[544 + m*16 + kg*4];
      b = MFMA(WE, ltr, b);
      b = MFMA(WE, ltf, b);
      aE[m] = b;
    }
    bf16x8 exf = zero8(), exr = zero8();
#pragma unroll
    for (int e=0; e<8; ++e){
      float v = fmaxf(aE[e>>2][e&3], 0.0f);
      unsigned short hb = f2bf(v);
      exf[e] = (short)hb;
      exr[e] = (short)f2bf(v - __uint_as_float(((unsigned)hb)<<16));
    }
#pragma unroll
    for (int m=0; m<8; ++m){
      float sc = (m==4 || m==5) ? L2F : L1F;
      bf16x8 wm = ldfragS(dWih0, m*16+cl, kg, sc);
      f32x4 b = *(const f32x4*)&sb[256 + m*16 + kg*4];
      b = MFMA(wm, exr, b);
      b = MFMA(wm, exf, b);
      dpre[m] = b;
    }
  }

  // reset state; reload rb1 with decoder layer-1 biases
#pragma unroll
  for (int e=0;e<8;++e){ cs0[e]=0.f; cs1[e]=0.f; }
  ph0 = zero8(); ph0r = zero8(); ph1 = zero8(); ph1r = zero8();

  __syncthreads();   // dec frags staged
#pragma unroll
  for (int m=0;m<8;++m) rb1[m] = *(const f32x4*)&sb[384 + m*16 + kg*4];

  const f32x4 obias = *(const f32x4*)&sb[512 + kg*4];
  float* __restrict__ ob = out + blockb*100;
  const int sobase = (w*16 + cl)*50;

  // ---- decoder prologue: t=0 layer0 (h0=0 -> z0 = dpre) ----
  activate(dpre, cs0, ph0, ph0r);

  // ================= decoder main (t = 0..18) =================
#pragma unroll 1
  for (int t=0; t<SEQT-1; ++t){
    asm volatile("" ::: "memory");
    // layer1 MFMAs for step t
#pragma unroll
    for (int m=0; m<8; ++m){
      bf16x8 fd = *(const bf16x8*)&sfrag[(1024 + m*64 + lane)*8];
      bf16x8 fc = *(const bf16x8*)&sfrag[( 512 + m*64 + lane)*8];
      f32x4 b = rb1[m];
      b = MFMA(fd, ph1r, b);
      b = MFMA(fd, ph1 , b);
      b = MFMA(fc, ph0r, b);
      b = MFMA(fc, ph0 , b);
      accB[m] = b;
    }
    // layer0 MFMAs for step t+1 (dpre + Whh0@(h0,res))
#pragma unroll
    for (int m=0; m<8; ++m){
      bf16x8 fa = *(const bf16x8*)&sfrag[(m*64 + lane)*8];
      f32x4 b = dpre[m];
      b = MFMA(fa, ph0r, b);
      b = MFMA(fa, ph0 , b);
      acc[m] = b;
    }
    activate(accB, cs1, ph1, ph1r);
    // output projection for step t (needs new ph1)
    bf16x8 fo = *(const bf16x8*)&sfrag[(1536 + lane)*8];
    f32x4 o = obias;
    o = MFMA(fo, ph1r, o);
    o = MFMA(fo, ph1 , o);
    activate(acc, cs0, ph0, ph0r);   // overlaps out-proj MFMAs
    // stage output
    int ts = (t >= 10) ? t-10 : t;
    if (kg == 0){
      sout[sobase + ts*5 + 0] = o[0];
      sout[sobase + ts*5 + 1] = o[1];
      sout[sobase + ts*5 + 2] = o[2];
      sout[sobase + ts*5 + 3] = o[3];
    } else if (kg == 1){
      sout[sobase + ts*5 + 4] = o[0];
    }
    if (t == 9){
      __syncthreads();
      for (int i=tid; i<3200; i+=256){
        int bb = i/50, off = i - bb*50;
        ob[bb*100 + off] = sout[i];
      }
      __syncthreads();
    }
  }
  // decoder epilogue: t=19 (layer1 + out-proj only)
  {
#pragma unroll
    for (int m=0; m<8; ++m){
      bf16x8 fd = *(const bf16x8*)&sfrag[(1024 + m*64 + lane)*8];
      bf16x8 fc = *(const bf16x8*)&sfrag[( 512 + m*64 + lane)*8];
      f32x4 b = rb1[m];
      b = MFMA(fd, ph1r, b);
      b = MFMA(fd, ph1 , b);
      b = MFMA(fc, ph0r, b);
      b = MFMA(fc, ph0 , b);
      accB[m] = b;
    }
    activate(accB, cs1, ph1, ph1r);
    bf16x8 fo = *(const bf16x8*)&sfrag[(1536 + lane)*8];
    f32x4 o = obias;
    o = MFMA(fo, ph1r, o);
    o = MFMA(fo, ph1 , o);
    if (kg == 0){
      sout[sobase + 45 + 0] = o[0];
      sout[sobase + 45 + 1] = o[1];
      sout[sobase + 45 + 2] = o[2];
      sout[sobase + 45 + 3] = o[3];
    } else if (kg == 1){
      sout[sobase + 45 + 4] = o[0];
    }
  }
  __syncthreads();
  for (int i=tid; i<3200; i+=256){
    int bb = i/50, off = i - bb*50;
    ob[bb*100 + 50 + off] = sout[i];
  }
}

extern "C" void kernel_launch(void* const* d_in, const int* in_sizes, int n_in,
                              void* d_out, int out_size, void* d_ws, size_t ws_size,
                              hipStream_t stream)
{
  const float* x     = (const float*)d_in[0];
  const float* eWih0 = (const float*)d_in[1];
  const float* eWhh0 = (const float*)d_in[2];
  const float* ebih0 = (const float*)d_in[3];
  const float* ebhh0 = (const float*)d_in[4];
  const float* eWih1 = (const float*)d_in[5];
  const float* eWhh1 = (const float*)d_in[6];
  const float* ebih1 = (const float*)d_in[7];
  const float* ebhh1 = (const float*)d_in[8];
  const float* bnW   = (const float*)d_in[9];
  const float* bnB   = (const float*)d_in[10];
  const float* exW   = (const float*)d_in[11];
  const float* exB   = (const float*)d_in[12];
  const float* dWih0 = (const float*)d_in[13];
  const float* dWhh0 = (const float*)d_in[14];
  const float* dbih0 = (const float*)d_in[15];
  const float* dbhh0 = (const float*)d_in[16];
  const float* dWih1 = (const float*)d_in[17];
  const float* dWhh1 = (const float*)d_in[18];
  const float* dbih1 = (const float*)d_in[19];
  const float* dbhh1 = (const float*)d_in[20];
  const float* outW  = (const float*)d_in[21];
  const float* outB  = (const float*)d_in[22];

  dim3 grid(BATCH / 64), block(256);
  hipLaunchKernelGGL(lstm_ae_mfma, grid, block, 0, stream,
                     x,
                     eWih0, eWhh0, ebih0, ebhh0,
                     eWih1, eWhh1, ebih1, ebhh1,
                     bnW, bnB, exW, exB,
                     dWih0, dWhh0, dbih0, dbhh0,
                     dWih1, dWhh1, dbih1, dbhh1,
                     outW, outB,
                     (float*)d_out);
}